// Round 1
// baseline (348.972 us; speedup 1.0000x reference)
//
#include <hip/hip_runtime.h>

#define K_CODES   1024
#define NTOK      131072
#define OUT_ELEMS 8388608
#define QX_OFF    8388608
#define LOSS_OFF  8519680

// ---------------- prep: per-code squared norms + zero the loss slot ----------------
__global__ void vq_prep_kernel(const float* __restrict__ lut,
                               float* __restrict__ norms,
                               float* __restrict__ d_out) {
    int code = blockIdx.x * blockDim.x + threadIdx.x;
    if (code == 0) d_out[LOSS_OFF] = 0.f;
    if (code < K_CODES) {
        const float4* c4 = reinterpret_cast<const float4*>(lut + code * 64);
        float s = 0.f;
#pragma unroll
        for (int i = 0; i < 16; ++i) {
            float4 v = c4[i];
            s += v.x * v.x + v.y * v.y + v.z * v.z + v.w * v.w;
        }
        norms[code] = s;
    }
}

// ---------------- main: 128 tokens/block, 8x8 register tile, fp32 VALU ----------------
// LDS (dynamic, 66048 B): xs[8192] | cs[8192] | cn/qsh[128]
__launch_bounds__(256, 2)
__global__ void vq_main_kernel(const float* __restrict__ x,
                               const float* __restrict__ lut,
                               const float* __restrict__ norms,
                               float* __restrict__ d_out) {
    extern __shared__ float sh[];
    float* xs = sh;               // 8192 floats, x tile, f4-swizzled
    float* cs = sh + 8192;        // 8192 floats, chunk / reduce / gathered codes
    float* cn = sh + 16384;       // 128 floats, chunk norms (later reused as qsh)
    int*   qsh = reinterpret_cast<int*>(sh + 16384);

    const int tid = threadIdx.x;
    const int t0  = blockIdx.x * 128;          // first token of this block
    const int b   = t0 >> 12;                  // batch index (4096 tokens per batch)
    const long xbase = (long)b * 262144 + (t0 & 4095);

    // ---- stage x tile: token t (0..127), dim d (0..63); coalesced global reads ----
#pragma unroll
    for (int it = 0; it < 32; ++it) {
        int e = tid + it * 256;
        int d = e >> 7;
        int t = e & 127;
        float v = x[xbase + (long)d * 4096 + t];
        int f4 = t * 16 + ((d >> 2) ^ (t >> 3));   // XOR-swizzled float4 slot
        xs[f4 * 4 + (d & 3)] = v;
    }

    const int row = tid >> 4;   // 0..15 : token group (8 tokens)
    const int col = tid & 15;   // 0..15 : code group  (8 codes)

    float best[8];
    int   bidx[8];
#pragma unroll
    for (int i = 0; i < 8; ++i) { best[i] = 3.4e38f; bidx[i] = 0; }

    float4* xs4 = reinterpret_cast<float4*>(xs);
    float4* cs4 = reinterpret_cast<float4*>(cs);
    const float4* lut4 = reinterpret_cast<const float4*>(lut);

    for (int ch = 0; ch < 8; ++ch) {
        int J0 = ch * 128;
        __syncthreads();          // cs free (previous chunk consumed)
        // stage code chunk (coalesced dwordx4), XOR-swizzled
#pragma unroll
        for (int it = 0; it < 8; ++it) {
            int g  = tid + it * 256;        // float4 index 0..2047
            int j  = g >> 4;
            int d4 = g & 15;
            float4 v = lut4[(J0 + j) * 16 + d4];
            cs4[j * 16 + (d4 ^ (j >> 3))] = v;
        }
        if (tid < 128) cn[tid] = norms[J0 + tid];
        __syncthreads();

        float acc[8][8];
#pragma unroll
        for (int i = 0; i < 8; ++i)
#pragma unroll
            for (int jj = 0; jj < 8; ++jj) acc[i][jj] = 0.f;

#pragma unroll 4
        for (int s = 0; s < 16; ++s) {
            float4 xf[8], cf[8];
#pragma unroll
            for (int i = 0; i < 8; ++i)
                xf[i] = xs4[(row * 8 + i) * 16 + (s ^ row)];
#pragma unroll
            for (int jj = 0; jj < 8; ++jj)
                cf[jj] = cs4[(col * 8 + jj) * 16 + (s ^ col)];
#pragma unroll
            for (int i = 0; i < 8; ++i)
#pragma unroll
                for (int jj = 0; jj < 8; ++jj)
                    acc[i][jj] += xf[i].x * cf[jj].x + xf[i].y * cf[jj].y
                                + xf[i].z * cf[jj].z + xf[i].w * cf[jj].w;
        }

        // running argmin (ascending code order -> first-min tie-break preserved)
#pragma unroll
        for (int jj = 0; jj < 8; ++jj) {
            float cnj   = cn[col * 8 + jj];
            int codeid  = J0 + col * 8 + jj;
#pragma unroll
            for (int i = 0; i < 8; ++i) {
                float v = cnj - 2.f * acc[i][jj];
                if (v < best[i]) { best[i] = v; bidx[i] = codeid; }
            }
        }
    }

    // ---- cross-thread argmin reduction (16 threads per token), stride 17 (bank-safe) ----
    __syncthreads();
    float* rv = cs;                                   // 128*17 = 2176
    int*   ri = reinterpret_cast<int*>(cs + 2176);    // 128*17
#pragma unroll
    for (int i = 0; i < 8; ++i) {
        int t = row * 8 + i;
        rv[t * 17 + col] = best[i];
        ri[t * 17 + col] = bidx[i];
    }
    __syncthreads();
    if (tid < 128) {
        int t = tid;
        float bv = rv[t * 17];
        int   bi = ri[t * 17];
#pragma unroll
        for (int c = 1; c < 16; ++c) {
            float v  = rv[t * 17 + c];
            int   ix = ri[t * 17 + c];
            if (v < bv || (v == bv && ix < bi)) { bv = v; bi = ix; }
        }
        qsh[t] = bi;                                   // overwrites cn (dead now)
        d_out[QX_OFF + t0 + t] = (float)bi;            // q_x as float-cast index
    }
    __syncthreads();

    // ---- gather chosen codes into cs as [d][128 tokens] (conflict-free epilogue reads) ----
    {
        int t = tid >> 1, half = tid & 1;
        int q = qsh[t];
        const float4* src = reinterpret_cast<const float4*>(lut + q * 64 + half * 32);
#pragma unroll
        for (int k = 0; k < 8; ++k) {
            float4 v = src[k];
            int dbase = half * 32 + k * 4;
            cs[(dbase + 0) * 128 + t] = v.x;
            cs[(dbase + 1) * 128 + t] = v.y;
            cs[(dbase + 2) * 128 + t] = v.z;
            cs[(dbase + 3) * 128 + t] = v.w;
        }
    }
    __syncthreads();

    // ---- epilogue: out = 2x - x_e (coalesced), accumulate loss ----
    float lsum = 0.f;
#pragma unroll
    for (int it = 0; it < 32; ++it) {
        int e = tid + it * 256;
        int d = e >> 7;
        int t = e & 127;
        int f4 = t * 16 + ((d >> 2) ^ (t >> 3));
        float xv = xs[f4 * 4 + (d & 3)];
        float cv = cs[d * 128 + t];
        float diff = xv - cv;
        lsum += diff * diff;
        d_out[xbase + (long)d * 4096 + t] = 2.f * xv - cv;
    }
#pragma unroll
    for (int off = 32; off >= 1; off >>= 1)
        lsum += __shfl_down(lsum, off, 64);
    if ((tid & 63) == 0)
        atomicAdd(&d_out[LOSS_OFF], lsum * (1.25f / 8388608.f));
}

extern "C" void kernel_launch(void* const* d_in, const int* in_sizes, int n_in,
                              void* d_out, int out_size, void* d_ws, size_t ws_size,
                              hipStream_t stream) {
    const float* x   = (const float*)d_in[0];   // [32,64,64,64] f32
    const float* lut = (const float*)d_in[1];   // [1024,64] f32
    float* out   = (float*)d_out;
    float* norms = (float*)d_ws;                // 1024 floats scratch

    vq_prep_kernel<<<4, 256, 0, stream>>>(lut, norms, out);

    const int lds_bytes = (8192 + 8192 + 128) * 4;   // 66048 B
    vq_main_kernel<<<NTOK / 128, 256, lds_bytes, stream>>>(x, lut, norms, out);
}

// Round 3
// 339.734 us; speedup vs baseline: 1.0272x; 1.0272x over previous
//
#include <hip/hip_runtime.h>

#define K_CODES   1024
#define QX_OFF    8388608
#define LOSS_OFF  8519680

// ---------------- prep: per-code squared norms + zero the loss slot ----------------
// NOTE: expression form is bit-exact-critical (matches round-1 pass). Do NOT rewrite
// as fmaf chains: norms feed argmin near-ties directly.
__global__ void vq_prep_kernel(const float* __restrict__ lut,
                               float* __restrict__ norms,
                               float* __restrict__ d_out) {
    int code = blockIdx.x * blockDim.x + threadIdx.x;
    if (code == 0) d_out[LOSS_OFF] = 0.f;
    if (code < K_CODES) {
        const float4* c4 = reinterpret_cast<const float4*>(lut + code * 64);
        float s = 0.f;
#pragma unroll
        for (int i = 0; i < 16; ++i) {
            float4 v = c4[i];
            s += v.x * v.x + v.y * v.y + v.z * v.z + v.w * v.w;
        }
        norms[code] = s;
    }
}

// ---------------- main: 128 tokens x 1024 codes per block, 8x8 fp32 register tile ----------------
// LDS layout (floats): xs4[2176 f4] | cs4[2176 f4] | cn/qsh[128]
// Padded-interleaved layout: slot(t, q) = t*17 + q  (odd f4 stride -> banks spread; the
// s index is a compile-time immediate in the inner loop: zero address VALU).
// Distance arithmetic expressions are verbatim round-1 (bit-exact argmin reproduction).
__launch_bounds__(256, 2)
__global__ void vq_main_kernel(const float* __restrict__ x,
                               const float* __restrict__ lut,
                               const float* __restrict__ norms,
                               float* __restrict__ d_out) {
    extern __shared__ float sh[];
    float4* xs4 = reinterpret_cast<float4*>(sh);           // 128 tokens * 17 f4
    float4* cs4 = reinterpret_cast<float4*>(sh + 8704);    // 128 codes  * 17 f4
    float*  cs  = sh + 8704;
    float*  cn  = sh + 17408;                              // 128 chunk norms
    int*    qsh = reinterpret_cast<int*>(sh + 17408);      // aliases cn (dead by then)

    const int tid = threadIdx.x;
    const int t0  = blockIdx.x * 128;
    const int b   = t0 >> 12;
    const long xbase = (long)b * 262144 + (t0 & 4095);

    // ---- stage x tile: transpose [d][t] -> [t][d-quad], b128 writes, coalesced b32 reads ----
    {
        int tt = tid & 31, qq = tid >> 5;
#pragma unroll
        for (int it = 0; it < 8; ++it) {
            int t = tt + (it & 3) * 32;
            int q = qq + (it >> 2) * 8;
            const float* xp = x + xbase + (long)(4 * q) * 4096 + t;
            float4 v;
            v.x = xp[0];
            v.y = xp[4096];
            v.z = xp[8192];
            v.w = xp[12288];
            xs4[t * 17 + q] = v;
        }
    }

    const int row = tid >> 4;   // 0..15 : thread's token sub-index (t = i*16 + row)
    const int col = tid & 15;   // 0..15 : thread's code  sub-index (j = jj*16 + col)

    float best[8];
    int   bidx[8];
#pragma unroll
    for (int i = 0; i < 8; ++i) { best[i] = 3.4e38f; bidx[i] = 0; }

    const float4* lut4   = reinterpret_cast<const float4*>(lut);
    const float4* xbase4 = xs4 + row * 17;
    const float4* cbase4 = cs4 + col * 17;

    for (int ch = 0; ch < 8; ++ch) {
        const int J0 = ch * 128;
        __syncthreads();                       // previous chunk fully consumed
        // stage code chunk: fully-coalesced b128 loads, padded b128 writes
#pragma unroll
        for (int it = 0; it < 8; ++it) {
            int g = tid + it * 256;
            int j = g >> 4, q = g & 15;
            cs4[j * 17 + q] = lut4[(J0 + j) * 16 + q];
        }
        if (tid < 128) cn[tid] = norms[J0 + tid];
        __syncthreads();

        float acc[8][8];
#pragma unroll
        for (int i = 0; i < 8; ++i)
#pragma unroll
            for (int jj = 0; jj < 8; ++jj) acc[i][jj] = 0.f;

#pragma unroll 8
        for (int s = 0; s < 16; ++s) {
            float4 xf[8], cf[8];
#pragma unroll
            for (int i = 0; i < 8; ++i)  xf[i]  = xbase4[i * 272 + s];   // broadcast x16 lanes
#pragma unroll
            for (int jj = 0; jj < 8; ++jj) cf[jj] = cbase4[jj * 272 + s]; // 16 addrs, banks spread
#pragma unroll
            for (int i = 0; i < 8; ++i)
#pragma unroll
                for (int jj = 0; jj < 8; ++jj)
                    acc[i][jj] += xf[i].x * cf[jj].x + xf[i].y * cf[jj].y
                                + xf[i].z * cf[jj].z + xf[i].w * cf[jj].w;
        }

        // running argmin; per-thread code sequence ascending -> first-min tie-break kept
#pragma unroll
        for (int jj = 0; jj < 8; ++jj) {
            float cnj  = cn[jj * 16 + col];
            int codeid = J0 + jj * 16 + col;
#pragma unroll
            for (int i = 0; i < 8; ++i) {
                float v = cnj - 2.f * acc[i][jj];
                if (v < best[i]) { best[i] = v; bidx[i] = codeid; }
            }
        }
    }

    // ---- cross-thread argmin reduction (16 threads per token), stride 17 (bank-safe) ----
    __syncthreads();
    float* rv = cs;                                  // 128*17
    int*   ri = reinterpret_cast<int*>(cs + 2176);   // 128*17
#pragma unroll
    for (int i = 0; i < 8; ++i) {
        int t = i * 16 + row;
        rv[t * 17 + col] = best[i];
        ri[t * 17 + col] = bidx[i];
    }
    __syncthreads();
    if (tid < 128) {
        float bv = rv[tid * 17];
        int   bi = ri[tid * 17];
#pragma unroll
        for (int c = 1; c < 16; ++c) {
            float v  = rv[tid * 17 + c];
            int   ix = ri[tid * 17 + c];
            if (v < bv || (v == bv && ix < bi)) { bv = v; bi = ix; }
        }
        qsh[tid] = bi;
        d_out[QX_OFF + t0 + tid] = (float)bi;
    }
    __syncthreads();

    // ---- gather chosen codes into cs as [d][128 tokens] ----
    {
        int t = tid >> 1, half = tid & 1;
        int q = qsh[t];
        const float4* src = reinterpret_cast<const float4*>(lut + q * 64 + half * 32);
#pragma unroll
        for (int k = 0; k < 8; ++k) {
            float4 v = src[k];
            int dbase = half * 32 + k * 4;
            cs[(dbase + 0) * 128 + t] = v.x;
            cs[(dbase + 1) * 128 + t] = v.y;
            cs[(dbase + 2) * 128 + t] = v.z;
            cs[(dbase + 3) * 128 + t] = v.w;
        }
    }
    __syncthreads();

    // ---- epilogue: out = 2x - x_e (coalesced), accumulate loss ----
    float lsum = 0.f;
    {
        int tt = tid & 31, qq = tid >> 5;
#pragma unroll
        for (int it = 0; it < 8; ++it) {
            int t = tt + (it & 3) * 32;
            int q = qq + (it >> 2) * 8;
            float4 xv = xs4[t * 17 + q];
            float c0 = cs[(4 * q + 0) * 128 + t];
            float c1 = cs[(4 * q + 1) * 128 + t];
            float c2 = cs[(4 * q + 2) * 128 + t];
            float c3 = cs[(4 * q + 3) * 128 + t];
            float* op = d_out + xbase + (long)(4 * q) * 4096 + t;
            op[0]     = 2.f * xv.x - c0;
            op[4096]  = 2.f * xv.y - c1;
            op[8192]  = 2.f * xv.z - c2;
            op[12288] = 2.f * xv.w - c3;
            float e0 = xv.x - c0, e1 = xv.y - c1, e2 = xv.z - c2, e3 = xv.w - c3;
            lsum += e0 * e0 + e1 * e1 + e2 * e2 + e3 * e3;
        }
    }
#pragma unroll
    for (int off = 32; off >= 1; off >>= 1)
        lsum += __shfl_down(lsum, off, 64);
    if ((tid & 63) == 0)
        atomicAdd(&d_out[LOSS_OFF], lsum * (1.25f / 8388608.f));
}

extern "C" void kernel_launch(void* const* d_in, const int* in_sizes, int n_in,
                              void* d_out, int out_size, void* d_ws, size_t ws_size,
                              hipStream_t stream) {
    const float* x   = (const float*)d_in[0];   // [32,64,64,64] f32
    const float* lut = (const float*)d_in[1];   // [1024,64] f32
    float* out   = (float*)d_out;
    float* norms = (float*)d_ws;                // 1024 floats scratch

    vq_prep_kernel<<<4, 256, 0, stream>>>(lut, norms, out);

    const int lds_bytes = (8704 + 8704 + 128) * 4;   // 70144 B -> 2 blocks/CU
    vq_main_kernel<<<1024, 256, lds_bytes, stream>>>(x, lut, norms, out);
}

// Round 4
// 303.474 us; speedup vs baseline: 1.1499x; 1.1195x over previous
//
#include <hip/hip_runtime.h>

#define K_CODES   1024
#define QX_OFF    8388608
#define LOSS_OFF  8519680
#define MARGIN    0.0625f

typedef __attribute__((ext_vector_type(8))) short bf16x8;
typedef __attribute__((ext_vector_type(4))) float f32x4;

__device__ __forceinline__ unsigned short rne_bf16(float f) {
    unsigned u = __float_as_uint(f);
    u += 0x7FFFu + ((u >> 16) & 1u);
    return (unsigned short)(u >> 16);
}
__device__ __forceinline__ float bf16_to_f(unsigned short h) {
    return __uint_as_float(((unsigned)h) << 16);
}
__device__ __forceinline__ unsigned long long pack4(unsigned short a, unsigned short b,
                                                    unsigned short c, unsigned short d) {
    return (unsigned long long)a | ((unsigned long long)b << 16)
         | ((unsigned long long)c << 32) | ((unsigned long long)d << 48);
}

// ---------------- prep: norms (EXACT round-1 expression), bf16-split codebook, zero loss/cnt ----
__global__ void vq_prep_kernel(const float* __restrict__ lut,
                               float* __restrict__ norms,
                               unsigned short* __restrict__ lutbf,   // [1024][128]: ch[64]|cl[64]
                               int* __restrict__ flagcnt,
                               float* __restrict__ d_out) {
    int c = blockIdx.x * 256 + threadIdx.x;
    if (c == 0) { d_out[LOSS_OFF] = 0.f; *flagcnt = 0; }
    if (c < K_CODES) {
        const float4* c4 = reinterpret_cast<const float4*>(lut + c * 64);
        float s = 0.f;
        unsigned short* hrow = lutbf + c * 128;
#pragma unroll
        for (int i = 0; i < 16; ++i) {
            float4 v = c4[i];
            s += v.x * v.x + v.y * v.y + v.z * v.z + v.w * v.w;   // verbatim round-1
            unsigned short h0 = rne_bf16(v.x), h1 = rne_bf16(v.y),
                           h2 = rne_bf16(v.z), h3 = rne_bf16(v.w);
            unsigned short l0 = rne_bf16(v.x - bf16_to_f(h0)), l1 = rne_bf16(v.y - bf16_to_f(h1)),
                           l2 = rne_bf16(v.z - bf16_to_f(h2)), l3 = rne_bf16(v.w - bf16_to_f(h3));
            *(unsigned long long*)(hrow + i * 4)      = pack4(h0, h1, h2, h3);
            *(unsigned long long*)(hrow + 64 + i * 4) = pack4(l0, l1, l2, l3);
        }
        norms[c] = s;
    }
}

// ---------------- kernel1: MFMA approx-distance screen ----------------
// Block: 64 tokens, 4 waves; chunks of 128 codes; K=192 via 6 k-steps over (xh|xl)x(ch|cl).
// LDS: A[64][128]bf16 swizzled (16K) | B[128][128]bf16 swizzled (32K) | cn[128] (512B)
__launch_bounds__(256, 3)
__global__ void vq_mfma_kernel(const float* __restrict__ x,
                               const uint4* __restrict__ lutbf4,
                               const float* __restrict__ norms,
                               float* __restrict__ qxf,
                               int* __restrict__ flaglist,
                               int* __restrict__ flagcnt) {
    __shared__ unsigned long long smll[6208];          // 49664 B
    char* smc = reinterpret_cast<char*>(smll);
    float* cnl = reinterpret_cast<float*>(smc + 49152);

    const int tid = threadIdx.x;
    const int t0  = blockIdx.x * 64;
    const int bb  = t0 >> 12;
    const long xbase = (long)bb * 262144 + (t0 & 4095);

    // ---- stage A: token t, dims as bf16 split; byte = t*256 + (2k ^ ((t&7)<<4)) ----
#pragma unroll
    for (int i = 0; i < 4; ++i) {
        int item = tid + 256 * i;             // 0..1023
        int t = item & 63, q = item >> 6;     // q = d-quad 0..15
        const float* xp = x + xbase + (long)(4 * q) * 4096 + t;
        float v0 = xp[0], v1 = xp[4096], v2 = xp[8192], v3 = xp[12288];
        unsigned short h0 = rne_bf16(v0), h1 = rne_bf16(v1), h2 = rne_bf16(v2), h3 = rne_bf16(v3);
        unsigned short l0 = rne_bf16(v0 - bf16_to_f(h0)), l1 = rne_bf16(v1 - bf16_to_f(h1)),
                       l2 = rne_bf16(v2 - bf16_to_f(h2)), l3 = rne_bf16(v3 - bf16_to_f(h3));
        int rowb = t * 256, swz = (t & 7) << 4;
        *(unsigned long long*)(smc + rowb + ((q * 8) ^ swz))        = pack4(h0, h1, h2, h3);
        *(unsigned long long*)(smc + rowb + ((128 + q * 8) ^ swz))  = pack4(l0, l1, l2, l3);
    }

    const int lane = tid & 63, w = tid >> 6;
    const int lcol = lane & 15, g = lane >> 4;
    const int tok  = w * 16 + lcol;
    const int g16  = g << 4;
    const char* aRow = smc + tok * 256;
    const int aswz = (tok & 7) << 4;
    const char* bRow = smc + 16384 + lcol * 256;
    const int bswz = (lane & 7) << 4;

    float b1[4], b2[4]; int i1[4];
#pragma unroll
    for (int r = 0; r < 4; ++r) { b1[r] = 3.4e38f; b2[r] = 3.4e38f; i1[r] = 0; }

    const int KA2[6] = {0, 64, 0, 64, 128, 192};     // byte offsets: xh,xh,xh,xh,xl,xl
    const int KB2[6] = {0, 64, 128, 192, 0, 64};     //               ch,ch,cl,cl,ch,ch

    for (int ch = 0; ch < 8; ++ch) {
        const int J0 = ch * 128;
        __syncthreads();
#pragma unroll
        for (int i = 0; i < 8; ++i) {
            int item = tid + 256 * i;          // 0..2047 16B-granules
            int c = item >> 4, gg = item & 15;
            uint4 v = lutbf4[(J0 + c) * 16 + gg];
            *(uint4*)(smc + 16384 + c * 256 + ((gg * 16) ^ ((c & 7) << 4))) = v;
        }
        if (tid < 128) cnl[tid] = norms[J0 + tid];
        __syncthreads();

        f32x4 acc[8];
#pragma unroll
        for (int ct = 0; ct < 8; ++ct) { f32x4 z = {0.f, 0.f, 0.f, 0.f}; acc[ct] = z; }

#pragma unroll
        for (int s = 0; s < 6; ++s) {
            bf16x8 af = *(const bf16x8*)(aRow + ((KA2[s] + g16) ^ aswz));
#pragma unroll
            for (int ct = 0; ct < 8; ++ct) {
                bf16x8 bf = *(const bf16x8*)(bRow + ct * 4096 + ((KB2[s] + g16) ^ bswz));
                acc[ct] = __builtin_amdgcn_mfma_f32_16x16x32_bf16(af, bf, acc[ct], 0, 0, 0);
            }
        }

        // approx distance + best1/best2 tracking (lane owns code = J0+ct*16+lcol, rows g*4+r)
#pragma unroll
        for (int ct = 0; ct < 8; ++ct) {
            float cnv = cnl[ct * 16 + lcol];
            int idx = J0 + ct * 16 + lcol;
#pragma unroll
            for (int r = 0; r < 4; ++r) {
                float v = fmaf(-2.f, acc[ct][r], cnv);
                bool lt = v < b1[r];
                float lose = lt ? b1[r] : v;
                b2[r] = fminf(b2[r], lose);
                if (lt) { b1[r] = v; i1[r] = idx; }
            }
        }
    }

    // ---- cross-lane reduce within each 16-lane group (cols of the tile) ----
#pragma unroll
    for (int m = 1; m <= 8; m <<= 1) {
#pragma unroll
        for (int r = 0; r < 4; ++r) {
            float ob1 = __shfl_xor(b1[r], m, 64);
            int   oi1 = __shfl_xor(i1[r], m, 64);
            float ob2 = __shfl_xor(b2[r], m, 64);
            bool take = (ob1 < b1[r]) || (ob1 == b1[r] && oi1 < i1[r]);
            float lose = take ? b1[r] : ob1;
            b2[r] = fminf(fminf(b2[r], ob2), lose);
            if (take) { b1[r] = ob1; i1[r] = oi1; }
        }
    }
    if (lcol == 0) {
#pragma unroll
        for (int r = 0; r < 4; ++r) {
            int token = t0 + w * 16 + g * 4 + r;
            qxf[token] = (float)i1[r];
            if (b2[r] - b1[r] <= MARGIN) {
                int slot = atomicAdd(flagcnt, 1);
                flaglist[slot] = token;
            }
        }
    }
}

// ---------------- kernel2: exact rescan of flagged tokens (verbatim round-3 arithmetic) ----
__global__ void vq_rescan_kernel(const float* __restrict__ x,
                                 const float* __restrict__ lut,
                                 const float* __restrict__ norms,
                                 float* __restrict__ qxf,
                                 const int* __restrict__ flaglist,
                                 const int* __restrict__ flagcnt) {
    __shared__ float4 xs4[64 * 17];
    __shared__ float4 cs4[128 * 17];
    __shared__ float  cn2[128];
    __shared__ int    tlist[64];
    float* csf = reinterpret_cast<float*>(cs4);

    const int tid = threadIdx.x;
    const int cnt = *flagcnt;

    for (int base = blockIdx.x * 64; base < cnt; base += 256 * 64) {
        int n = cnt - base; if (n > 64) n = 64;
        __syncthreads();
        if (tid < 64) tlist[tid] = flaglist[base + (tid < n ? tid : 0)];
        __syncthreads();
        // stage x for the 64 (scattered) tokens
#pragma unroll
        for (int i = 0; i < 4; ++i) {
            int item = tid + 256 * i;
            int slot = item & 63, q = item >> 6;
            int tkn = tlist[slot];
            const float* xp = x + (long)(tkn >> 12) * 262144 + (tkn & 4095);
            float4 v;
            v.x = xp[(long)(4 * q + 0) * 4096];
            v.y = xp[(long)(4 * q + 1) * 4096];
            v.z = xp[(long)(4 * q + 2) * 4096];
            v.w = xp[(long)(4 * q + 3) * 4096];
            xs4[slot * 17 + q] = v;
        }

        const int row = tid >> 4, col = tid & 15;
        float best[4]; int bidx[4];
#pragma unroll
        for (int i2 = 0; i2 < 4; ++i2) { best[i2] = 3.4e38f; bidx[i2] = 0; }

        const float4* lut4 = reinterpret_cast<const float4*>(lut);
        const float4* xb4 = xs4 + row * 17;
        const float4* cb4 = cs4 + col * 17;

        for (int chk = 0; chk < 8; ++chk) {
            const int J0 = chk * 128;
            __syncthreads();
#pragma unroll
            for (int i3 = 0; i3 < 8; ++i3) {
                int g2 = tid + i3 * 256;
                int j = g2 >> 4, q = g2 & 15;
                cs4[j * 17 + q] = lut4[(J0 + j) * 16 + q];
            }
            if (tid < 128) cn2[tid] = norms[J0 + tid];
            __syncthreads();

            float acc[4][8];
#pragma unroll
            for (int i2 = 0; i2 < 4; ++i2)
#pragma unroll
                for (int jj = 0; jj < 8; ++jj) acc[i2][jj] = 0.f;

#pragma unroll 8
            for (int s = 0; s < 16; ++s) {
                float4 xf[4], cf[8];
#pragma unroll
                for (int i2 = 0; i2 < 4; ++i2) xf[i2] = xb4[i2 * 272 + s];
#pragma unroll
                for (int jj = 0; jj < 8; ++jj) cf[jj] = cb4[jj * 272 + s];
#pragma unroll
                for (int i2 = 0; i2 < 4; ++i2)
#pragma unroll
                    for (int jj = 0; jj < 8; ++jj)
                        acc[i2][jj] += xf[i2].x * cf[jj].x + xf[i2].y * cf[jj].y
                                     + xf[i2].z * cf[jj].z + xf[i2].w * cf[jj].w;
            }

#pragma unroll
            for (int jj = 0; jj < 8; ++jj) {
                float cnj = cn2[jj * 16 + col];
                int codeid = J0 + jj * 16 + col;
#pragma unroll
                for (int i2 = 0; i2 < 4; ++i2) {
                    float v = cnj - 2.f * acc[i2][jj];
                    if (v < best[i2]) { best[i2] = v; bidx[i2] = codeid; }
                }
            }
        }

        // cross-thread reduce (16 threads per token), stride 17
        __syncthreads();
        float* rv = csf;                                  // 64*17
        int*   ri = reinterpret_cast<int*>(csf + 1088);   // 64*17
#pragma unroll
        for (int i2 = 0; i2 < 4; ++i2) {
            int t = i2 * 16 + row;
            rv[t * 17 + col] = best[i2];
            ri[t * 17 + col] = bidx[i2];
        }
        __syncthreads();
        if (tid < 64) {
            float bv = rv[tid * 17];
            int   bi = ri[tid * 17];
#pragma unroll
            for (int c = 1; c < 16; ++c) {
                float v = rv[tid * 17 + c];
                int  ix = ri[tid * 17 + c];
                if (v < bv || (v == bv && ix < bi)) { bv = v; bi = ix; }
            }
            if (tid < n) qxf[tlist[tid]] = (float)bi;
        }
    }
}

// ---------------- kernel3: epilogue — out = 2x - x_e, loss ----------------
__global__ void vq_epilogue_kernel(const float* __restrict__ x,
                                   const float* __restrict__ lut,
                                   float* __restrict__ d_out) {
    __shared__ float cs[8192];     // [d][128 tokens]
    __shared__ int qsh[128];
    const int tid = threadIdx.x;
    const int t0 = blockIdx.x * 128;
    const int bb = t0 >> 12;
    const long xbase = (long)bb * 262144 + (t0 & 4095);

    if (tid < 128) qsh[tid] = (int)d_out[QX_OFF + t0 + tid];
    __syncthreads();
    {
        int t = tid >> 1, half = tid & 1;
        int q = qsh[t];
        const float4* src = reinterpret_cast<const float4*>(lut + q * 64 + half * 32);
#pragma unroll
        for (int k = 0; k < 8; ++k) {
            float4 v = src[k];
            int dbase = half * 32 + k * 4;
            cs[(dbase + 0) * 128 + t] = v.x;
            cs[(dbase + 1) * 128 + t] = v.y;
            cs[(dbase + 2) * 128 + t] = v.z;
            cs[(dbase + 3) * 128 + t] = v.w;
        }
    }
    __syncthreads();

    float lsum = 0.f;
    {
        int tt = tid & 31, qq = tid >> 5;
#pragma unroll
        for (int it = 0; it < 8; ++it) {
            int t = tt + (it & 3) * 32;
            int q = qq + (it >> 2) * 8;
            const float* xp = x + xbase + (long)(4 * q) * 4096 + t;
            float x0 = xp[0], x1 = xp[4096], x2 = xp[8192], x3 = xp[12288];
            float c0 = cs[(4 * q + 0) * 128 + t];
            float c1 = cs[(4 * q + 1) * 128 + t];
            float c2 = cs[(4 * q + 2) * 128 + t];
            float c3 = cs[(4 * q + 3) * 128 + t];
            float* op = d_out + xbase + (long)(4 * q) * 4096 + t;
            op[0]     = 2.f * x0 - c0;
            op[4096]  = 2.f * x1 - c1;
            op[8192]  = 2.f * x2 - c2;
            op[12288] = 2.f * x3 - c3;
            float e0 = x0 - c0, e1 = x1 - c1, e2 = x2 - c2, e3 = x3 - c3;
            lsum += e0 * e0 + e1 * e1 + e2 * e2 + e3 * e3;
        }
    }
#pragma unroll
    for (int off = 32; off >= 1; off >>= 1)
        lsum += __shfl_down(lsum, off, 64);
    if ((tid & 63) == 0)
        atomicAdd(&d_out[LOSS_OFF], lsum * (1.25f / 8388608.f));
}

extern "C" void kernel_launch(void* const* d_in, const int* in_sizes, int n_in,
                              void* d_out, int out_size, void* d_ws, size_t ws_size,
                              hipStream_t stream) {
    const float* x   = (const float*)d_in[0];   // [32,64,64,64] f32
    const float* lut = (const float*)d_in[1];   // [1024,64] f32
    float* out = (float*)d_out;
    char* ws = (char*)d_ws;
    float* norms            = (float*)ws;                       // 4 KB
    unsigned short* lutbf   = (unsigned short*)(ws + 4096);     // 256 KB
    int* flagcnt            = (int*)(ws + 266240);
    int* flaglist           = (int*)(ws + 266256);              // up to 512 KB

    vq_prep_kernel<<<4, 256, 0, stream>>>(lut, norms, lutbf, flagcnt, out);
    vq_mfma_kernel<<<2048, 256, 0, stream>>>(x, (const uint4*)lutbf, norms,
                                             out + QX_OFF, flaglist, flagcnt);
    vq_rescan_kernel<<<256, 256, 0, stream>>>(x, lut, norms, out + QX_OFF,
                                              flaglist, flagcnt);
    vq_epilogue_kernel<<<1024, 256, 0, stream>>>(x, lut, out);
}